// Round 2
// baseline (1341.234 us; speedup 1.0000x reference)
//
#include <hip/hip_runtime.h>

// Y[j, b, i] = ((2*x[i,j]+1) >> min(2047-b, 31)) & 1, float32, shape [2048,2048,64].
// Nonzero only for shift = 2047-b <= 11 (12 of 2048 columns). Pure write-bound.
//
// Grid-stride quad loop with threads_total = 524288 (multiple of 16*2048):
//   q = t + it*524288  =>  i4 = t&15 const, b = (t>>4)&2047 const, j = j0 + 16*it.
// So hot/cold is thread-invariant: cold threads (99.4%) run a pure fill loop,
// hot threads read x (512 KB, L2-resident) once per 16 B stored.

#define EMB 2048
#define BATCH 64
#define NBLOCKS 2048
#define NTHREADS (NBLOCKS * 256u)               // 524288
#define NQUADS   ((unsigned int)EMB * EMB * BATCH / 4u)  // 1<<26
#define ITERS    (NQUADS / NTHREADS)            // 128

__global__ __launch_bounds__(256) void emb_bits_kernel(
    const int* __restrict__ x, float4* __restrict__ out) {
    unsigned int t  = blockIdx.x * 256u + threadIdx.x;
    unsigned int i4 = t & 15u;                  // float4 index within batch dim
    unsigned int jb = t >> 4;
    unsigned int b  = jb & 2047u;
    unsigned int j0 = jb >> 11;                 // 0..15, advances by 16 per iter
    int shift = 2047 - (int)b;

    float4* p = out + t;
    if (shift > 11) {
        // Cold path: pure streaming zero-fill, 1 KiB/wave per store.
        const float4 z = make_float4(0.f, 0.f, 0.f, 0.f);
        #pragma unroll 8
        for (unsigned int it = 0; it < ITERS; ++it) {
            *p = z;
            p += NTHREADS;
        }
    } else {
        // Hot path (12/2048 of threads): data-dependent bits.
        unsigned int i0 = i4 * 4u;
        #pragma unroll 2
        for (unsigned int it = 0; it < ITERS; ++it) {
            unsigned int j = j0 + (it << 4);
            int v0 = 2 * x[(i0 + 0) * EMB + j] + 1;
            int v1 = 2 * x[(i0 + 1) * EMB + j] + 1;
            int v2 = 2 * x[(i0 + 2) * EMB + j] + 1;
            int v3 = 2 * x[(i0 + 3) * EMB + j] + 1;
            float4 val;
            val.x = (float)((v0 >> shift) & 1);
            val.y = (float)((v1 >> shift) & 1);
            val.z = (float)((v2 >> shift) & 1);
            val.w = (float)((v3 >> shift) & 1);
            *p = val;
            p += NTHREADS;
        }
    }
}

extern "C" void kernel_launch(void* const* d_in, const int* in_sizes, int n_in,
                              void* d_out, int out_size, void* d_ws, size_t ws_size,
                              hipStream_t stream) {
    const int* x = (const int*)d_in[0];
    float4* out = (float4*)d_out;
    emb_bits_kernel<<<dim3(NBLOCKS), dim3(256), 0, stream>>>(x, out);
}

// Round 3
// 1049.006 us; speedup vs baseline: 1.2786x; 1.2786x over previous
//
#include <hip/hip_runtime.h>

// Y[j, b, i] = ((2*x[i,j]+1) >> min(2047-b, 31)) & 1, float32, shape [2048,2048,64].
// Nonzero only for shift = 2047-b <= 11 (12 of 2048 columns). Pure write-bound (1 GiB out).
//
// R3: linear block-local sweep. 16384 blocks x 256 threads; each block writes a
// contiguous 64 KiB chunk (16 x float4 per thread, fully unrolled). Preserves the
// dense sliding-window store pattern of R1 (dispatch-order locality) while cutting
// block count 16x (R1's 262144 blocks risked being dispatch-rate-bound) and
// avoiding R2's 8 MiB-strided scatter (which cost 3x in HBM write efficiency).

#define EMB 2048
#define NQUADS (1u << 26)          // 2048*2048*64/4
#define BLOCKS 16384
#define CHUNK (NQUADS / BLOCKS)    // 4096 quads = 64 KiB per block
#define ITERS (CHUNK / 256u)       // 16

__global__ __launch_bounds__(256) void emb_bits_kernel(
    const int* __restrict__ x, float4* __restrict__ out) {
    unsigned int base = blockIdx.x * CHUNK + threadIdx.x;
    unsigned int i0   = (threadIdx.x & 15u) * 4u;   // batch offset, iteration-invariant

    #pragma unroll
    for (unsigned int it = 0; it < ITERS; ++it) {
        unsigned int q  = base + it * 256u;
        unsigned int jb = q >> 4;
        unsigned int b  = jb & 2047u;
        int shift = 2047 - (int)b;

        float4 val = make_float4(0.f, 0.f, 0.f, 0.f);
        if (shift <= 11) {                          // 12/2048 of iterations
            unsigned int j = jb >> 11;
            int v0 = 2 * x[(i0 + 0) * EMB + j] + 1;
            int v1 = 2 * x[(i0 + 1) * EMB + j] + 1;
            int v2 = 2 * x[(i0 + 2) * EMB + j] + 1;
            int v3 = 2 * x[(i0 + 3) * EMB + j] + 1;
            val.x = (float)((v0 >> shift) & 1);
            val.y = (float)((v1 >> shift) & 1);
            val.z = (float)((v2 >> shift) & 1);
            val.w = (float)((v3 >> shift) & 1);
        }
        out[q] = val;
    }
}

extern "C" void kernel_launch(void* const* d_in, const int* in_sizes, int n_in,
                              void* d_out, int out_size, void* d_ws, size_t ws_size,
                              hipStream_t stream) {
    const int* x = (const int*)d_in[0];
    float4* out = (float4*)d_out;
    emb_bits_kernel<<<dim3(BLOCKS), dim3(256), 0, stream>>>(x, out);
}

// Round 5
// 1028.284 us; speedup vs baseline: 1.3043x; 1.0202x over previous
//
#include <hip/hip_runtime.h>

// Y[j, b, i] = ((2*x[i,j]+1) >> min(2047-b, 31)) & 1, float32, shape [2048,2048,64].
// Nonzero only for shift = 2047-b <= 11 (12 of 2048 columns). Pure write-bound (1 GiB out).
//
// R5: R1's best-measured structure (one float4 store per thread, 262144 blocks —
// dense dispatch-ordered sliding-window sweep, ~6.7 TB/s write) + nontemporal
// stores via clang ext_vector_type (HIP_vector_type float4 is rejected by the
// builtin). Streaming 1 GiB with zero reuse -> evict-first hint cuts L2/L3
// pressure. R2 taught: never stride the store pattern.

#define EMB 2048
#define BATCH 64

typedef float vfloat4 __attribute__((ext_vector_type(4)));

__global__ __launch_bounds__(256) void emb_bits_kernel(
    const int* __restrict__ x, vfloat4* __restrict__ out) {
    // quad index over the whole output: 2048*2048*64/4 = 2^26 quads
    unsigned int q  = blockIdx.x * 256u + threadIdx.x;
    unsigned int i4 = q & 15u;        // which float4 within the 64-wide batch dim
    unsigned int jb = q >> 4;         // j*2048 + b
    unsigned int b  = jb & 2047u;
    unsigned int j  = jb >> 11;
    int shift = 2047 - (int)b;

    vfloat4 val = (vfloat4){0.f, 0.f, 0.f, 0.f};
    if (shift <= 11) {                // only last 12 columns carry data
        unsigned int i0 = i4 * 4u;
        int v0 = 2 * x[(i0 + 0) * EMB + j] + 1;
        int v1 = 2 * x[(i0 + 1) * EMB + j] + 1;
        int v2 = 2 * x[(i0 + 2) * EMB + j] + 1;
        int v3 = 2 * x[(i0 + 3) * EMB + j] + 1;
        val.x = (float)((v0 >> shift) & 1);
        val.y = (float)((v1 >> shift) & 1);
        val.z = (float)((v2 >> shift) & 1);
        val.w = (float)((v3 >> shift) & 1);
    }
    __builtin_nontemporal_store(val, &out[q]);
}

extern "C" void kernel_launch(void* const* d_in, const int* in_sizes, int n_in,
                              void* d_out, int out_size, void* d_ws, size_t ws_size,
                              hipStream_t stream) {
    const int* x = (const int*)d_in[0];
    vfloat4* out = (vfloat4*)d_out;
    const unsigned int quads = (unsigned int)EMB * EMB * BATCH / 4u; // 67108864
    dim3 grid(quads / 256u);                                        // 262144 blocks
    emb_bits_kernel<<<grid, dim3(256), 0, stream>>>(x, out);
}